// Round 17
// baseline (305.834 us; speedup 1.0000x reference)
//
#include <hip/hip_runtime.h>
#include <hip/hip_bf16.h>
#include <math.h>

#define NEG_SLOPE 0.01f

typedef short short8 __attribute__((ext_vector_type(8)));
typedef float f32x4 __attribute__((ext_vector_type(4)));

__device__ __forceinline__ float lrelu(float v) { return v > 0.0f ? v : NEG_SLOPE * v; }

__device__ __forceinline__ short f2bf(float f) {
    __hip_bfloat16 h = __float2bfloat16(f);
    return __builtin_bit_cast(short, h);
}

// ---------------------------------------------------------------------------
// pack_all: fp32 [K][N] -> bf16 fragment-native layout.
// frag f = ((t*K32 + ks)*4 + n); lane l, elem e:
//   col = t*64 + n*16 + (l&15), k = ks*32 + (l>>4)*8 + e
// ---------------------------------------------------------------------------
__global__ __launch_bounds__(256) void pack_all(
    const float* __restrict__ W4, const float* __restrict__ Wf,
    const float* __restrict__ Wmu, const float* __restrict__ Wlv,
    const float* __restrict__ Wd1, const float* __restrict__ Wd2,
    const float* __restrict__ Wd3, const float* __restrict__ W2,
    const float* __restrict__ W3,
    short* __restrict__ F4, short* __restrict__ Ff, short* __restrict__ Fmuvl,
    short* __restrict__ Fd1, short* __restrict__ Fd2, short* __restrict__ Fd3,
    short* __restrict__ F2, short* __restrict__ F3)
{
    int bid = blockIdx.x;
    const float* src = nullptr; short* dst = nullptr; int K = 0, N = 0; int muvl = 0;
    if      (bid < 64)   { src = W4;  dst = F4;    K = 128;  N = 1024; }
    else if (bid < 576)  { src = Wf;  dst = Ff;    K = 1024; N = 1024; bid -= 64; }
    else if (bid < 832)  { src = nullptr; dst = Fmuvl; K = 1024; N = 512; muvl = 1; bid -= 576; }
    else if (bid < 960)  { src = Wd1; dst = Fd1;   K = 256;  N = 1024; bid -= 832; }
    else if (bid < 1472) { src = Wd2; dst = Fd2;   K = 1024; N = 1024; bid -= 960; }
    else if (bid < 1664) { src = Wd3; dst = Fd3;   K = 1024; N = 384;  bid -= 1472; }
    else if (bid < 1666) { src = W2;  dst = F2;    K = 64;   N = 64;   bid -= 1664; }
    else                 { src = W3;  dst = F3;    K = 64;   N = 128;  bid -= 1666; }

    const int fragid = bid * 4 + (threadIdx.x >> 6);
    const int lane   = threadIdx.x & 63;
    const int K32    = K >> 5;
    const int t   = fragid / (K32 * 4);
    const int rem = fragid - t * K32 * 4;
    const int ks  = rem >> 2;
    const int n   = rem & 3;
    const int col   = t * 64 + n * 16 + (lane & 15);
    const int kbase = ks * 32 + (lane >> 4) * 8;

    short8 v;
#pragma unroll
    for (int e = 0; e < 8; ++e) {
        float f;
        if (muvl) f = (col < 256) ? Wmu[(size_t)(kbase + e) * 256 + col]
                                  : Wlv[(size_t)(kbase + e) * 256 + col - 256];
        else      f = src[(size_t)(kbase + e) * N + col];
        v[e] = f2bf(f);
    }
    *(short8*)&dst[(size_t)fragid * 512 + lane * 8] = v;
}

// ---------------------------------------------------------------------------
// h3_kernel: per-point MLP 3->64->64->128, barrier-free, wave-private LDS.
// Output: A-fragments packed to global:
//   h3p[((b*32+g)*16 + ks*4+m)*512 + lane*8]
// ---------------------------------------------------------------------------
__global__ __launch_bounds__(128, 2) void h3_kernel(
    const float* __restrict__ x, const int* __restrict__ lengths,
    const float* __restrict__ W1, const float* __restrict__ b1,
    const float* __restrict__ b2, const float* __restrict__ b3,
    const short* __restrict__ F2, const short* __restrict__ F3,
    short* __restrict__ h3p)
{
    const int tid  = threadIdx.x;
    const int b    = blockIdx.x & 127;
    const int c2   = blockIdx.x >> 7;
    const int lane = tid & 63;
    const int w    = tid >> 6;
    const int g    = c2 * 2 + w;
    const int len  = lengths[b];
    if (g * 64 >= len) return;

    __shared__ short S[16384];
    short* Aw = S + w * 8192;
    const int gid = b * 2048 + g * 64 + lane;

    {   // P0: h1
        const float x0 = x[gid * 3 + 0];
        const float x1 = x[gid * 3 + 1];
        const float x2 = x[gid * 3 + 2];
#pragma unroll
        for (int q = 0; q < 8; ++q) {
            short8 pv;
#pragma unroll
            for (int e = 0; e < 8; ++e) {
                int c = q * 8 + e;
                float v = b1[c];
                v = fmaf(x0, W1[c], v);
                v = fmaf(x1, W1[64 + c], v);
                v = fmaf(x2, W1[128 + c], v);
                pv[e] = f2bf(lrelu(v));
            }
            *(short8*)&Aw[lane * 64 + ((q ^ (lane & 7)) * 8)] = pv;
        }
    }

    {   // L2
        short8 a2[4][2];
#pragma unroll
        for (int m = 0; m < 4; ++m)
#pragma unroll
            for (int ks = 0; ks < 2; ++ks) {
                int rl = m * 16 + (lane & 15);
                int kch = ks * 4 + (lane >> 4);
                a2[m][ks] = *(const short8*)&Aw[rl * 64 + ((kch ^ (rl & 7)) * 8)];
            }
        short8 b2f[2][4];
#pragma unroll
        for (int ks = 0; ks < 2; ++ks)
#pragma unroll
            for (int n = 0; n < 4; ++n)
                b2f[ks][n] = *(const short8*)&F2[(size_t)(ks * 4 + n) * 512 + lane * 8];

        f32x4 acc2[4][4];
#pragma unroll
        for (int m = 0; m < 4; ++m)
#pragma unroll
            for (int n = 0; n < 4; ++n) acc2[m][n] = 0;
#pragma unroll
        for (int ks = 0; ks < 2; ++ks)
#pragma unroll
            for (int n = 0; n < 4; ++n)
#pragma unroll
                for (int m = 0; m < 4; ++m)
                    acc2[m][n] = __builtin_amdgcn_mfma_f32_16x16x32_bf16(
                        a2[m][ks], b2f[ks][n], acc2[m][n], 0, 0, 0);

#pragma unroll
        for (int n = 0; n < 4; ++n) {
            int col = n * 16 + (lane & 15);
            float bv = b2[col];
            int colch = col >> 3;
#pragma unroll
            for (int m = 0; m < 4; ++m)
#pragma unroll
                for (int r = 0; r < 4; ++r) {
                    int rl = m * 16 + (lane >> 4) * 4 + r;
                    Aw[4096 + rl * 64 + ((colch ^ (rl & 7)) * 8) + (col & 7)] =
                        f2bf(lrelu(acc2[m][n][r] + bv));
                }
        }
    }

    {   // L3
        short8 a3[4][2];
#pragma unroll
        for (int m = 0; m < 4; ++m)
#pragma unroll
            for (int ks = 0; ks < 2; ++ks) {
                int rl = m * 16 + (lane & 15);
                int kch = ks * 4 + (lane >> 4);
                a3[m][ks] = *(const short8*)&Aw[4096 + rl * 64 + ((kch ^ (rl & 7)) * 8)];
            }
#pragma unroll
        for (int half = 0; half < 2; ++half) {
            short8 b3f[2][4];
#pragma unroll
            for (int ks = 0; ks < 2; ++ks)
#pragma unroll
                for (int n = 0; n < 4; ++n)
                    b3f[ks][n] = *(const short8*)&F3[(size_t)(half * 8 + ks * 4 + n) * 512 + lane * 8];

            f32x4 acc3[4][4];
#pragma unroll
            for (int m = 0; m < 4; ++m)
#pragma unroll
                for (int n = 0; n < 4; ++n) acc3[m][n] = 0;
#pragma unroll
            for (int ks = 0; ks < 2; ++ks)
#pragma unroll
                for (int n = 0; n < 4; ++n)
#pragma unroll
                    for (int m = 0; m < 4; ++m)
                        acc3[m][n] = __builtin_amdgcn_mfma_f32_16x16x32_bf16(
                            a3[m][ks], b3f[ks][n], acc3[m][n], 0, 0, 0);

#pragma unroll
            for (int n = 0; n < 4; ++n) {
                int col = half * 64 + n * 16 + (lane & 15);
                float bv = b3[col];
                int colch = col >> 3;
#pragma unroll
                for (int m = 0; m < 4; ++m)
#pragma unroll
                    for (int r = 0; r < 4; ++r) {
                        int rl = m * 16 + (lane >> 4) * 4 + r;
                        Aw[rl * 128 + ((colch ^ (rl & 7)) * 8) + (col & 7)] =
                            f2bf(lrelu(acc3[m][n][r] + bv));
                    }
            }
        }
    }

    const size_t obase = ((size_t)(b * 32 + g) * 16) * 512 + lane * 8;
#pragma unroll
    for (int ks = 0; ks < 4; ++ks)
#pragma unroll
        for (int m = 0; m < 4; ++m) {
            int rl = m * 16 + (lane & 15);
            int ch = (ks * 4 + (lane >> 4)) ^ (rl & 7);
            short8 af = *(const short8*)&Aw[rl * 128 + ch * 8];
            *(short8*)&h3p[obase + (size_t)(ks * 4 + m) * 512] = af;
        }
}

// ---------------------------------------------------------------------------
// l4_pool v6 + occupancy hint 5 (LDS allows 5 blocks/CU; VGPR 84 <= 102 cap):
// 64-row chunks, 2x16KB LDS double buffer, ONE barrier per chunk.
// grid (128 b, 4 ch, 8 rs).
// ---------------------------------------------------------------------------
__global__ __launch_bounds__(256, 5) void l4_pool_kernel(
    const short* __restrict__ h3p, const int* __restrict__ lengths,
    const short* __restrict__ F4, float* __restrict__ part)
{
    const int tid = threadIdx.x, lane = tid & 63, w = tid >> 6;
    const int b = blockIdx.x, ch = blockIdx.y, rs = blockIdx.z;
    const int len = lengths[b];
    const int live64 = (len + 63) >> 6;
    const int cbeg = rs * 4;
    int cend = cbeg + 4; if (cend > live64) cend = live64;
    if (cbeg >= cend) return;

    __shared__ short L[16384];                   // 2 x 8192-short (16KB) buffers

    const int t = ch * 4 + w;
    short8 bfr[4][4];
#pragma unroll
    for (int ks = 0; ks < 4; ++ks)
#pragma unroll
        for (int n = 0; n < 4; ++n)
            bfr[ks][n] = *(const short8*)&F4[(size_t)((t * 4 + ks) * 4 + n) * 512 + lane * 8];

    const int partial = (len & 63) ? (live64 - 1) : -1;
    const int rem = len & 63;

    f32x4 rmax[4];
#pragma unroll
    for (int n = 0; n < 4; ++n)
#pragma unroll
        for (int rr = 0; rr < 4; ++rr) rmax[n][rr] = -INFINITY;

    const size_t bb = (size_t)b * 32;
    short8 stg[4];
    {   // prolog: stage chunk cbeg into buf0
        const size_t fb = (bb + cbeg) * 16 * 512;
#pragma unroll
        for (int pass = 0; pass < 4; ++pass)
            stg[pass] = *(const short8*)&h3p[fb + (size_t)(pass * 256 + tid) * 8];
#pragma unroll
        for (int pass = 0; pass < 4; ++pass)
            *(short8*)&L[(pass * 256 + tid) * 8] = stg[pass];
    }
    __syncthreads();

    for (int c = cbeg; c < cend; ++c) {
        const int p2 = (c - cbeg) & 1;
        if (c + 1 < cend) {
            const size_t fb = (bb + c + 1) * 16 * 512;
#pragma unroll
            for (int pass = 0; pass < 4; ++pass)
                stg[pass] = *(const short8*)&h3p[fb + (size_t)(pass * 256 + tid) * 8];
        }

        const short* Lb = L + p2 * 8192;
#pragma unroll
        for (int mh = 0; mh < 2; ++mh) {
            f32x4 acc[2][4];
#pragma unroll
            for (int j = 0; j < 2; ++j)
#pragma unroll
                for (int n = 0; n < 4; ++n) acc[j][n] = 0;
#pragma unroll
            for (int ks = 0; ks < 4; ++ks) {
                short8 a0 = *(const short8*)&Lb[(ks * 4 + mh * 2 + 0) * 512 + lane * 8];
                short8 a1 = *(const short8*)&Lb[(ks * 4 + mh * 2 + 1) * 512 + lane * 8];
#pragma unroll
                for (int n = 0; n < 4; ++n) {
                    acc[0][n] = __builtin_amdgcn_mfma_f32_16x16x32_bf16(a0, bfr[ks][n], acc[0][n], 0, 0, 0);
                    acc[1][n] = __builtin_amdgcn_mfma_f32_16x16x32_bf16(a1, bfr[ks][n], acc[1][n], 0, 0, 0);
                }
            }
            if (c == partial) {
#pragma unroll
                for (int j = 0; j < 2; ++j)
#pragma unroll
                    for (int n = 0; n < 4; ++n)
#pragma unroll
                        for (int rr = 0; rr < 4; ++rr) {
                            int row = mh * 32 + j * 16 + (lane >> 4) * 4 + rr;
                            rmax[n][rr] = fmaxf(rmax[n][rr],
                                (row < rem) ? acc[j][n][rr] : -INFINITY);
                        }
            } else {
#pragma unroll
                for (int j = 0; j < 2; ++j)
#pragma unroll
                    for (int n = 0; n < 4; ++n)
#pragma unroll
                        for (int rr = 0; rr < 4; ++rr)
                            rmax[n][rr] = fmaxf(rmax[n][rr], acc[j][n][rr]);
            }
        }

        if (c + 1 < cend) {
            short* Ln = L + (p2 ^ 1) * 8192;
#pragma unroll
            for (int pass = 0; pass < 4; ++pass)
                *(short8*)&Ln[(pass * 256 + tid) * 8] = stg[pass];
        }
        __syncthreads();
    }

#pragma unroll
    for (int n = 0; n < 4; ++n) {
        float v = fmaxf(fmaxf(rmax[n][0], rmax[n][1]), fmaxf(rmax[n][2], rmax[n][3]));
        v = fmaxf(v, __shfl_xor(v, 16));
        v = fmaxf(v, __shfl_xor(v, 32));
        if (lane < 16)
            part[((size_t)b * 8 + rs) * 1024 + ch * 256 + w * 64 + n * 16 + lane] = v;
    }
}

// ---------------------------------------------------------------------------
// reduce: fold live row-slice partials, + b4, lrelu -> pooled bf16.
// ---------------------------------------------------------------------------
__global__ __launch_bounds__(256) void reduce_pool_kernel(
    const float* __restrict__ part, const int* __restrict__ lengths,
    const float* __restrict__ b4, short* __restrict__ pooled)
{
    const int b = blockIdx.x;
    const int nlive = (lengths[b] + 255) >> 8;   // 1..8
    for (int i = threadIdx.x; i < 1024; i += 256) {
        float m = part[((size_t)b * 8 + 0) * 1024 + i];
        for (int j = 1; j < nlive; ++j)
            m = fmaxf(m, part[((size_t)b * 8 + j) * 1024 + i]);
        pooled[(size_t)b * 1024 + i] = f2bf(lrelu(m + b4[i]));
    }
}

// ---------------------------------------------------------------------------
// gemm16: 1-wave blocks, 16 cols x 32 rows per wave, FULL-K B preload.
// grid (Nout/16, 4 rowhalves). EPI: 0 = bias->fp32, 1 = bias+lrelu->bf16,
// 2 = mu|lv split (c0<256 -> bias/outF, else bias2/outF2, fp32).
// ---------------------------------------------------------------------------
template<int K32, int EPI>
__global__ __launch_bounds__(64) void gemm16(
    const short* __restrict__ A, const short* __restrict__ Wfrag,
    const float* __restrict__ bias, const float* __restrict__ bias2,
    float* __restrict__ outF, float* __restrict__ outF2,
    short* __restrict__ outB, int Nout)
{
    const int lane = threadIdx.x;
    const int cbb = blockIdx.x, rh = blockIdx.y;
    const int K = K32 * 32;
    const int t = cbb >> 2, n = cbb & 3;

    short8 bf[K32];
#pragma unroll
    for (int ks = 0; ks < K32; ++ks)
        bf[ks] = *(const short8*)&Wfrag[(size_t)((t * K32 + ks) * 4 + n) * 512 + lane * 8];

    const int arow0 = rh * 32 + (lane & 15);
    const int koff  = (lane >> 4) * 8;
    f32x4 acc[2];
    acc[0] = 0; acc[1] = 0;
#pragma unroll
    for (int ks = 0; ks < K32; ++ks) {
        short8 a0 = *(const short8*)&A[(size_t)arow0 * K + ks * 32 + koff];
        short8 a1 = *(const short8*)&A[(size_t)(arow0 + 16) * K + ks * 32 + koff];
        acc[0] = __builtin_amdgcn_mfma_f32_16x16x32_bf16(a0, bf[ks], acc[0], 0, 0, 0);
        acc[1] = __builtin_amdgcn_mfma_f32_16x16x32_bf16(a1, bf[ks], acc[1], 0, 0, 0);
    }

    const int c0 = cbb * 16;
    const int cl = lane & 15;
    if (EPI == 2) {
        const float* bs = (c0 < 256) ? bias : bias2;
        float* of = (c0 < 256) ? outF : outF2;
        int col = (c0 & 255) + cl;
        float bv = bs[col];
#pragma unroll
        for (int m = 0; m < 2; ++m)
#pragma unroll
            for (int rr = 0; rr < 4; ++rr) {
                int row = rh * 32 + m * 16 + (lane >> 4) * 4 + rr;
                of[(size_t)row * 256 + col] = acc[m][rr] + bv;
            }
    } else {
        int col = c0 + cl;
        float bv = bias[col];
#pragma unroll
        for (int m = 0; m < 2; ++m)
#pragma unroll
            for (int rr = 0; rr < 4; ++rr) {
                int row = rh * 32 + m * 16 + (lane >> 4) * 4 + rr;
                float v = acc[m][rr] + bv;
                if (EPI == 1) outB[(size_t)row * Nout + col] = f2bf(lrelu(v));
                else          outF[(size_t)row * Nout + col] = v;
            }
    }
}

// ---------------------------------------------------------------------------
// gemmBN: 256 thr = 4 waves stacked in M (32 rows each), 16 cols, full-K B
// preload, fused BatchNorm (bias cancels) + lrelu -> bf16. grid (Nout/16).
// ZIN: A built on the fly as z = mu + eps*exp(0.5*lv) (fp32 inputs).
// ---------------------------------------------------------------------------
template<int K32, bool ZIN>
__global__ __launch_bounds__(256) void gemmBN(
    const short* __restrict__ A, const float* __restrict__ muv,
    const float* __restrict__ lvv, const float* __restrict__ eps,
    const short* __restrict__ Wfrag,
    const float* __restrict__ g, const float* __restrict__ be,
    short* __restrict__ outB, int Nout)
{
    __shared__ float bns[4][16];
    __shared__ float bnq[4][16];

    const int tid = threadIdx.x, lane = tid & 63, w = tid >> 6;
    const int cbb = blockIdx.x;
    const int K = K32 * 32;
    const int t = cbb >> 2, n = cbb & 3;

    short8 bf[K32];
#pragma unroll
    for (int ks = 0; ks < K32; ++ks)
        bf[ks] = *(const short8*)&Wfrag[(size_t)((t * K32 + ks) * 4 + n) * 512 + lane * 8];

    const int arow0 = w * 32 + (lane & 15);
    const int koff  = (lane >> 4) * 8;
    f32x4 acc[2];
    acc[0] = 0; acc[1] = 0;
#pragma unroll
    for (int ks = 0; ks < K32; ++ks) {
        short8 a0, a1;
        if (ZIN) {
#pragma unroll
            for (int e = 0; e < 8; ++e) {
                int k = ks * 32 + koff + e;
                size_t i0 = (size_t)arow0 * 256 + k;
                size_t i1 = (size_t)(arow0 + 16) * 256 + k;
                a0[e] = f2bf(fmaf(eps[i0], expf(0.5f * lvv[i0]), muv[i0]));
                a1[e] = f2bf(fmaf(eps[i1], expf(0.5f * lvv[i1]), muv[i1]));
            }
        } else {
            a0 = *(const short8*)&A[(size_t)arow0 * K + ks * 32 + koff];
            a1 = *(const short8*)&A[(size_t)(arow0 + 16) * K + ks * 32 + koff];
        }
        acc[0] = __builtin_amdgcn_mfma_f32_16x16x32_bf16(a0, bf[ks], acc[0], 0, 0, 0);
        acc[1] = __builtin_amdgcn_mfma_f32_16x16x32_bf16(a1, bf[ks], acc[1], 0, 0, 0);
    }

    // BN stats over the block's 128 rows
    float s = 0.f, q = 0.f;
#pragma unroll
    for (int m = 0; m < 2; ++m)
#pragma unroll
        for (int rr = 0; rr < 4; ++rr) {
            float v = acc[m][rr];
            s += v; q = fmaf(v, v, q);
        }
    s += __shfl_xor(s, 16); s += __shfl_xor(s, 32);
    q += __shfl_xor(q, 16); q += __shfl_xor(q, 32);
    if (lane < 16) { bns[w][lane] = s; bnq[w][lane] = q; }
    __syncthreads();

    const int cl = lane & 15;
    float st = bns[0][cl] + bns[1][cl] + bns[2][cl] + bns[3][cl];
    float qt = bnq[0][cl] + bnq[1][cl] + bnq[2][cl] + bnq[3][cl];
    float mean = st * (1.0f / 128.0f);
    float var  = qt * (1.0f / 128.0f) - mean * mean;
    float rs   = 1.0f / sqrtf(var + 1e-5f);
    const int col = cbb * 16 + cl;
    float gg = g[col] * rs;
    float bb = be[col] - mean * gg;

#pragma unroll
    for (int m = 0; m < 2; ++m)
#pragma unroll
        for (int rr = 0; rr < 4; ++rr) {
            int row = w * 32 + m * 16 + (lane >> 4) * 4 + rr;
            outB[(size_t)row * Nout + col] = f2bf(lrelu(fmaf(acc[m][rr], gg, bb)));
        }
}

// ---------------------------------------------------------------------------
extern "C" void kernel_launch(void* const* d_in, const int* in_sizes, int n_in,
                              void* d_out, int out_size, void* d_ws, size_t ws_size,
                              hipStream_t stream)
{
    const float* x       = (const float*)d_in[0];
    const int*   lengths = (const int*)  d_in[1];
    const float* eps     = (const float*)d_in[2];
    const float* W1  = (const float*)d_in[3];  const float* b1  = (const float*)d_in[4];
    const float* W2  = (const float*)d_in[5];  const float* b2  = (const float*)d_in[6];
    const float* W3  = (const float*)d_in[7];  const float* b3  = (const float*)d_in[8];
    const float* W4  = (const float*)d_in[9];  const float* b4  = (const float*)d_in[10];
    const float* Wf  = (const float*)d_in[11]; const float* bf  = (const float*)d_in[12];
    const float* Wmu = (const float*)d_in[13]; const float* bmu = (const float*)d_in[14];
    const float* Wlv = (const float*)d_in[15]; const float* blv = (const float*)d_in[16];
    const float* Wd1 = (const float*)d_in[17];
    const float* g1  = (const float*)d_in[19]; const float* be1 = (const float*)d_in[20];
    const float* Wd2 = (const float*)d_in[21];
    const float* g2  = (const float*)d_in[23]; const float* be2 = (const float*)d_in[24];
    const float* Wd3 = (const float*)d_in[25]; const float* bd3 = (const float*)d_in[26];
    // bd1, bd2 provably cancel inside BatchNorm

    float* out = (float*)d_out;
    float* y_out  = out;               // [128,384]
    float* mu_out = out + 49152;       // [128,256]
    float* lv_out = out + 81920;       // [128,256]

    // ---- workspace layout (bytes) ----
    char* ws = (char*)d_ws;
    short* F4    = (short*)(ws + 0);
    short* Ff    = (short*)(ws + 262144);
    short* Fmuvl = (short*)(ws + 2359296);
    short* Fd1   = (short*)(ws + 3407872);
    short* Fd2   = (short*)(ws + 3932160);
    short* Fd3   = (short*)(ws + 6029312);
    short* F2    = (short*)(ws + 6815744);
    short* F3    = (short*)(ws + 6823936);
    short* h3p   = (short*)(ws + 6840320);     // 64MB (dead after l4_pool)
    float* part  = (float*)(ws + 73949184);    // 128*8*1024 f32 = 4MB
    // post-l4 buffers overlay the (dead) h3p region:
    short* pooled = (short*)(ws + 6840320 + 0);
    short* ebuf   = (short*)(ws + 6840320 + 262144);
    short* d1v    = (short*)(ws + 6840320 + 524288);
    short* d2v    = (short*)(ws + 6840320 + 786432);

    // 0) pack all MFMA weights
    pack_all<<<1670, 256, 0, stream>>>(W4, Wf, Wmu, Wlv, Wd1, Wd2, Wd3, W2, W3,
                                       F4, Ff, Fmuvl, Fd1, Fd2, Fd3, F2, F3);
    // 1) per-point MLP -> packed h3 fragments
    h3_kernel<<<2048, 128, 0, stream>>>(x, lengths, W1, b1, b2, b3, F2, F3, h3p);
    // 2) L4 + masked max-pool (v6 schedule, occupancy hint 5)
    l4_pool_kernel<<<dim3(128, 4, 8), 256, 0, stream>>>(h3p, lengths, F4, part);
    // 3) finish pool (+b4, lrelu) -> pooled bf16
    reduce_pool_kernel<<<128, 256, 0, stream>>>(part, lengths, b4, pooled);
    // 4) e = lrelu(pooled @ Wf + bf) -> bf16
    gemm16<32, 1><<<dim3(64, 4), 64, 0, stream>>>(pooled, Ff, bf, nullptr,
                                                  nullptr, nullptr, ebuf, 1024);
    // 5) mu | logvar (fp32 straight to d_out)
    gemm16<32, 2><<<dim3(32, 4), 64, 0, stream>>>(ebuf, Fmuvl, bmu, blv,
                                                  mu_out, lv_out, nullptr, 256);
    // 6) decoder 1: z built on the fly (mu,lv,eps), Linear+BN+lrelu -> bf16
    gemmBN<8, true><<<64, 256, 0, stream>>>(nullptr, mu_out, lv_out, eps,
                                            Fd1, g1, be1, d1v, 1024);
    // 7) decoder 2: Linear+BN+lrelu -> bf16
    gemmBN<32, false><<<64, 256, 0, stream>>>(d1v, nullptr, nullptr, nullptr,
                                              Fd2, g2, be2, d2v, 1024);
    // 8) final linear -> y (fp32)
    gemm16<32, 0><<<dim3(24, 4), 64, 0, stream>>>(d2v, Fd3, bd3, nullptr,
                                                  y_out, nullptr, nullptr, 384);
}

// Round 18
// 206.103 us; speedup vs baseline: 1.4839x; 1.4839x over previous
//
#include <hip/hip_runtime.h>
#include <hip/hip_bf16.h>
#include <math.h>

#define NEG_SLOPE 0.01f

typedef short short8 __attribute__((ext_vector_type(8)));
typedef float f32x4 __attribute__((ext_vector_type(4)));

__device__ __forceinline__ float lrelu(float v) { return v > 0.0f ? v : NEG_SLOPE * v; }

__device__ __forceinline__ short f2bf(float f) {
    __hip_bfloat16 h = __float2bfloat16(f);
    return __builtin_bit_cast(short, h);
}

// ---------------------------------------------------------------------------
// pack_all: fp32 [K][N] -> bf16 fragment-native layout.
// frag f = ((t*K32 + ks)*4 + n); lane l, elem e:
//   col = t*64 + n*16 + (l&15), k = ks*32 + (l>>4)*8 + e
// ---------------------------------------------------------------------------
__global__ __launch_bounds__(256) void pack_all(
    const float* __restrict__ W4, const float* __restrict__ Wf,
    const float* __restrict__ Wmu, const float* __restrict__ Wlv,
    const float* __restrict__ Wd1, const float* __restrict__ Wd2,
    const float* __restrict__ Wd3, const float* __restrict__ W2,
    const float* __restrict__ W3,
    short* __restrict__ F4, short* __restrict__ Ff, short* __restrict__ Fmuvl,
    short* __restrict__ Fd1, short* __restrict__ Fd2, short* __restrict__ Fd3,
    short* __restrict__ F2, short* __restrict__ F3)
{
    int bid = blockIdx.x;
    const float* src = nullptr; short* dst = nullptr; int K = 0, N = 0; int muvl = 0;
    if      (bid < 64)   { src = W4;  dst = F4;    K = 128;  N = 1024; }
    else if (bid < 576)  { src = Wf;  dst = Ff;    K = 1024; N = 1024; bid -= 64; }
    else if (bid < 832)  { src = nullptr; dst = Fmuvl; K = 1024; N = 512; muvl = 1; bid -= 576; }
    else if (bid < 960)  { src = Wd1; dst = Fd1;   K = 256;  N = 1024; bid -= 832; }
    else if (bid < 1472) { src = Wd2; dst = Fd2;   K = 1024; N = 1024; bid -= 960; }
    else if (bid < 1664) { src = Wd3; dst = Fd3;   K = 1024; N = 384;  bid -= 1472; }
    else if (bid < 1666) { src = W2;  dst = F2;    K = 64;   N = 64;   bid -= 1664; }
    else                 { src = W3;  dst = F3;    K = 64;   N = 128;  bid -= 1666; }

    const int fragid = bid * 4 + (threadIdx.x >> 6);
    const int lane   = threadIdx.x & 63;
    const int K32    = K >> 5;
    const int t   = fragid / (K32 * 4);
    const int rem = fragid - t * K32 * 4;
    const int ks  = rem >> 2;
    const int n   = rem & 3;
    const int col   = t * 64 + n * 16 + (lane & 15);
    const int kbase = ks * 32 + (lane >> 4) * 8;

    short8 v;
#pragma unroll
    for (int e = 0; e < 8; ++e) {
        float f;
        if (muvl) f = (col < 256) ? Wmu[(size_t)(kbase + e) * 256 + col]
                                  : Wlv[(size_t)(kbase + e) * 256 + col - 256];
        else      f = src[(size_t)(kbase + e) * N + col];
        v[e] = f2bf(f);
    }
    *(short8*)&dst[(size_t)fragid * 512 + lane * 8] = v;
}

// ---------------------------------------------------------------------------
// h3_kernel: per-point MLP 3->64->64->128, barrier-free, wave-private LDS.
// Output: A-fragments packed to global:
//   h3p[((b*32+g)*16 + ks*4+m)*512 + lane*8]
// ---------------------------------------------------------------------------
__global__ __launch_bounds__(128, 2) void h3_kernel(
    const float* __restrict__ x, const int* __restrict__ lengths,
    const float* __restrict__ W1, const float* __restrict__ b1,
    const float* __restrict__ b2, const float* __restrict__ b3,
    const short* __restrict__ F2, const short* __restrict__ F3,
    short* __restrict__ h3p)
{
    const int tid  = threadIdx.x;
    const int b    = blockIdx.x & 127;
    const int c2   = blockIdx.x >> 7;
    const int lane = tid & 63;
    const int w    = tid >> 6;
    const int g    = c2 * 2 + w;
    const int len  = lengths[b];
    if (g * 64 >= len) return;

    __shared__ short S[16384];
    short* Aw = S + w * 8192;
    const int gid = b * 2048 + g * 64 + lane;

    {   // P0: h1
        const float x0 = x[gid * 3 + 0];
        const float x1 = x[gid * 3 + 1];
        const float x2 = x[gid * 3 + 2];
#pragma unroll
        for (int q = 0; q < 8; ++q) {
            short8 pv;
#pragma unroll
            for (int e = 0; e < 8; ++e) {
                int c = q * 8 + e;
                float v = b1[c];
                v = fmaf(x0, W1[c], v);
                v = fmaf(x1, W1[64 + c], v);
                v = fmaf(x2, W1[128 + c], v);
                pv[e] = f2bf(lrelu(v));
            }
            *(short8*)&Aw[lane * 64 + ((q ^ (lane & 7)) * 8)] = pv;
        }
    }

    {   // L2
        short8 a2[4][2];
#pragma unroll
        for (int m = 0; m < 4; ++m)
#pragma unroll
            for (int ks = 0; ks < 2; ++ks) {
                int rl = m * 16 + (lane & 15);
                int kch = ks * 4 + (lane >> 4);
                a2[m][ks] = *(const short8*)&Aw[rl * 64 + ((kch ^ (rl & 7)) * 8)];
            }
        short8 b2f[2][4];
#pragma unroll
        for (int ks = 0; ks < 2; ++ks)
#pragma unroll
            for (int n = 0; n < 4; ++n)
                b2f[ks][n] = *(const short8*)&F2[(size_t)(ks * 4 + n) * 512 + lane * 8];

        f32x4 acc2[4][4];
#pragma unroll
        for (int m = 0; m < 4; ++m)
#pragma unroll
            for (int n = 0; n < 4; ++n) acc2[m][n] = 0;
#pragma unroll
        for (int ks = 0; ks < 2; ++ks)
#pragma unroll
            for (int n = 0; n < 4; ++n)
#pragma unroll
                for (int m = 0; m < 4; ++m)
                    acc2[m][n] = __builtin_amdgcn_mfma_f32_16x16x32_bf16(
                        a2[m][ks], b2f[ks][n], acc2[m][n], 0, 0, 0);

#pragma unroll
        for (int n = 0; n < 4; ++n) {
            int col = n * 16 + (lane & 15);
            float bv = b2[col];
            int colch = col >> 3;
#pragma unroll
            for (int m = 0; m < 4; ++m)
#pragma unroll
                for (int r = 0; r < 4; ++r) {
                    int rl = m * 16 + (lane >> 4) * 4 + r;
                    Aw[4096 + rl * 64 + ((colch ^ (rl & 7)) * 8) + (col & 7)] =
                        f2bf(lrelu(acc2[m][n][r] + bv));
                }
        }
    }

    {   // L3
        short8 a3[4][2];
#pragma unroll
        for (int m = 0; m < 4; ++m)
#pragma unroll
            for (int ks = 0; ks < 2; ++ks) {
                int rl = m * 16 + (lane & 15);
                int kch = ks * 4 + (lane >> 4);
                a3[m][ks] = *(const short8*)&Aw[4096 + rl * 64 + ((kch ^ (rl & 7)) * 8)];
            }
#pragma unroll
        for (int half = 0; half < 2; ++half) {
            short8 b3f[2][4];
#pragma unroll
            for (int ks = 0; ks < 2; ++ks)
#pragma unroll
                for (int n = 0; n < 4; ++n)
                    b3f[ks][n] = *(const short8*)&F3[(size_t)(half * 8 + ks * 4 + n) * 512 + lane * 8];

            f32x4 acc3[4][4];
#pragma unroll
            for (int m = 0; m < 4; ++m)
#pragma unroll
                for (int n = 0; n < 4; ++n) acc3[m][n] = 0;
#pragma unroll
            for (int ks = 0; ks < 2; ++ks)
#pragma unroll
                for (int n = 0; n < 4; ++n)
#pragma unroll
                    for (int m = 0; m < 4; ++m)
                        acc3[m][n] = __builtin_amdgcn_mfma_f32_16x16x32_bf16(
                            a3[m][ks], b3f[ks][n], acc3[m][n], 0, 0, 0);

#pragma unroll
            for (int n = 0; n < 4; ++n) {
                int col = half * 64 + n * 16 + (lane & 15);
                float bv = b3[col];
                int colch = col >> 3;
#pragma unroll
                for (int m = 0; m < 4; ++m)
#pragma unroll
                    for (int r = 0; r < 4; ++r) {
                        int rl = m * 16 + (lane >> 4) * 4 + r;
                        Aw[rl * 128 + ((colch ^ (rl & 7)) * 8) + (col & 7)] =
                            f2bf(lrelu(acc3[m][n][r] + bv));
                    }
            }
        }
    }

    const size_t obase = ((size_t)(b * 32 + g) * 16) * 512 + lane * 8;
#pragma unroll
    for (int ks = 0; ks < 4; ++ks)
#pragma unroll
        for (int m = 0; m < 4; ++m) {
            int rl = m * 16 + (lane & 15);
            int ch = (ks * 4 + (lane >> 4)) ^ (rl & 7);
            short8 af = *(const short8*)&Aw[rl * 128 + ch * 8];
            *(short8*)&h3p[obase + (size_t)(ks * 4 + m) * 512] = af;
        }
}

// ---------------------------------------------------------------------------
// l4_pool v6 + occupancy hint 4 (VGPR cap 128 >= 84 need -> no spill; allows
// 4 blocks/CU vs hint-3's 3): 64-row chunks, 2x16KB LDS double buffer, ONE
// barrier per chunk. grid (128 b, 4 ch, 8 rs).
// ---------------------------------------------------------------------------
__global__ __launch_bounds__(256, 4) void l4_pool_kernel(
    const short* __restrict__ h3p, const int* __restrict__ lengths,
    const short* __restrict__ F4, float* __restrict__ part)
{
    const int tid = threadIdx.x, lane = tid & 63, w = tid >> 6;
    const int b = blockIdx.x, ch = blockIdx.y, rs = blockIdx.z;
    const int len = lengths[b];
    const int live64 = (len + 63) >> 6;
    const int cbeg = rs * 4;
    int cend = cbeg + 4; if (cend > live64) cend = live64;
    if (cbeg >= cend) return;

    __shared__ short L[16384];                   // 2 x 8192-short (16KB) buffers

    const int t = ch * 4 + w;
    short8 bfr[4][4];
#pragma unroll
    for (int ks = 0; ks < 4; ++ks)
#pragma unroll
        for (int n = 0; n < 4; ++n)
            bfr[ks][n] = *(const short8*)&F4[(size_t)((t * 4 + ks) * 4 + n) * 512 + lane * 8];

    const int partial = (len & 63) ? (live64 - 1) : -1;
    const int rem = len & 63;

    f32x4 rmax[4];
#pragma unroll
    for (int n = 0; n < 4; ++n)
#pragma unroll
        for (int rr = 0; rr < 4; ++rr) rmax[n][rr] = -INFINITY;

    const size_t bb = (size_t)b * 32;
    short8 stg[4];
    {   // prolog: stage chunk cbeg into buf0
        const size_t fb = (bb + cbeg) * 16 * 512;
#pragma unroll
        for (int pass = 0; pass < 4; ++pass)
            stg[pass] = *(const short8*)&h3p[fb + (size_t)(pass * 256 + tid) * 8];
#pragma unroll
        for (int pass = 0; pass < 4; ++pass)
            *(short8*)&L[(pass * 256 + tid) * 8] = stg[pass];
    }
    __syncthreads();

    for (int c = cbeg; c < cend; ++c) {
        const int p2 = (c - cbeg) & 1;
        if (c + 1 < cend) {
            const size_t fb = (bb + c + 1) * 16 * 512;
#pragma unroll
            for (int pass = 0; pass < 4; ++pass)
                stg[pass] = *(const short8*)&h3p[fb + (size_t)(pass * 256 + tid) * 8];
        }

        const short* Lb = L + p2 * 8192;
#pragma unroll
        for (int mh = 0; mh < 2; ++mh) {
            f32x4 acc[2][4];
#pragma unroll
            for (int j = 0; j < 2; ++j)
#pragma unroll
                for (int n = 0; n < 4; ++n) acc[j][n] = 0;
#pragma unroll
            for (int ks = 0; ks < 4; ++ks) {
                short8 a0 = *(const short8*)&Lb[(ks * 4 + mh * 2 + 0) * 512 + lane * 8];
                short8 a1 = *(const short8*)&Lb[(ks * 4 + mh * 2 + 1) * 512 + lane * 8];
#pragma unroll
                for (int n = 0; n < 4; ++n) {
                    acc[0][n] = __builtin_amdgcn_mfma_f32_16x16x32_bf16(a0, bfr[ks][n], acc[0][n], 0, 0, 0);
                    acc[1][n] = __builtin_amdgcn_mfma_f32_16x16x32_bf16(a1, bfr[ks][n], acc[1][n], 0, 0, 0);
                }
            }
            if (c == partial) {
#pragma unroll
                for (int j = 0; j < 2; ++j)
#pragma unroll
                    for (int n = 0; n < 4; ++n)
#pragma unroll
                        for (int rr = 0; rr < 4; ++rr) {
                            int row = mh * 32 + j * 16 + (lane >> 4) * 4 + rr;
                            rmax[n][rr] = fmaxf(rmax[n][rr],
                                (row < rem) ? acc[j][n][rr] : -INFINITY);
                        }
            } else {
#pragma unroll
                for (int j = 0; j < 2; ++j)
#pragma unroll
                    for (int n = 0; n < 4; ++n)
#pragma unroll
                        for (int rr = 0; rr < 4; ++rr)
                            rmax[n][rr] = fmaxf(rmax[n][rr], acc[j][n][rr]);
            }
        }

        if (c + 1 < cend) {
            short* Ln = L + (p2 ^ 1) * 8192;
#pragma unroll
            for (int pass = 0; pass < 4; ++pass)
                *(short8*)&Ln[(pass * 256 + tid) * 8] = stg[pass];
        }
        __syncthreads();
    }

#pragma unroll
    for (int n = 0; n < 4; ++n) {
        float v = fmaxf(fmaxf(rmax[n][0], rmax[n][1]), fmaxf(rmax[n][2], rmax[n][3]));
        v = fmaxf(v, __shfl_xor(v, 16));
        v = fmaxf(v, __shfl_xor(v, 32));
        if (lane < 16)
            part[((size_t)b * 8 + rs) * 1024 + ch * 256 + w * 64 + n * 16 + lane] = v;
    }
}

// ---------------------------------------------------------------------------
// reduce: fold live row-slice partials, + b4, lrelu -> pooled bf16.
// ---------------------------------------------------------------------------
__global__ __launch_bounds__(256) void reduce_pool_kernel(
    const float* __restrict__ part, const int* __restrict__ lengths,
    const float* __restrict__ b4, short* __restrict__ pooled)
{
    const int b = blockIdx.x;
    const int nlive = (lengths[b] + 255) >> 8;   // 1..8
    for (int i = threadIdx.x; i < 1024; i += 256) {
        float m = part[((size_t)b * 8 + 0) * 1024 + i];
        for (int j = 1; j < nlive; ++j)
            m = fmaxf(m, part[((size_t)b * 8 + j) * 1024 + i]);
        pooled[(size_t)b * 1024 + i] = f2bf(lrelu(m + b4[i]));
    }
}

// ---------------------------------------------------------------------------
// gemm16: 1-wave blocks, 16 cols x 32 rows per wave, FULL-K B preload.
// grid (Nout/16, 4 rowhalves). EPI: 0 = bias->fp32, 1 = bias+lrelu->bf16,
// 2 = mu|lv split (c0<256 -> bias/outF, else bias2/outF2, fp32).
// ---------------------------------------------------------------------------
template<int K32, int EPI>
__global__ __launch_bounds__(64) void gemm16(
    const short* __restrict__ A, const short* __restrict__ Wfrag,
    const float* __restrict__ bias, const float* __restrict__ bias2,
    float* __restrict__ outF, float* __restrict__ outF2,
    short* __restrict__ outB, int Nout)
{
    const int lane = threadIdx.x;
    const int cbb = blockIdx.x, rh = blockIdx.y;
    const int K = K32 * 32;
    const int t = cbb >> 2, n = cbb & 3;

    short8 bf[K32];
#pragma unroll
    for (int ks = 0; ks < K32; ++ks)
        bf[ks] = *(const short8*)&Wfrag[(size_t)((t * K32 + ks) * 4 + n) * 512 + lane * 8];

    const int arow0 = rh * 32 + (lane & 15);
    const int koff  = (lane >> 4) * 8;
    f32x4 acc[2];
    acc[0] = 0; acc[1] = 0;
#pragma unroll
    for (int ks = 0; ks < K32; ++ks) {
        short8 a0 = *(const short8*)&A[(size_t)arow0 * K + ks * 32 + koff];
        short8 a1 = *(const short8*)&A[(size_t)(arow0 + 16) * K + ks * 32 + koff];
        acc[0] = __builtin_amdgcn_mfma_f32_16x16x32_bf16(a0, bf[ks], acc[0], 0, 0, 0);
        acc[1] = __builtin_amdgcn_mfma_f32_16x16x32_bf16(a1, bf[ks], acc[1], 0, 0, 0);
    }

    const int c0 = cbb * 16;
    const int cl = lane & 15;
    if (EPI == 2) {
        const float* bs = (c0 < 256) ? bias : bias2;
        float* of = (c0 < 256) ? outF : outF2;
        int col = (c0 & 255) + cl;
        float bv = bs[col];
#pragma unroll
        for (int m = 0; m < 2; ++m)
#pragma unroll
            for (int rr = 0; rr < 4; ++rr) {
                int row = rh * 32 + m * 16 + (lane >> 4) * 4 + rr;
                of[(size_t)row * 256 + col] = acc[m][rr] + bv;
            }
    } else {
        int col = c0 + cl;
        float bv = bias[col];
#pragma unroll
        for (int m = 0; m < 2; ++m)
#pragma unroll
            for (int rr = 0; rr < 4; ++rr) {
                int row = rh * 32 + m * 16 + (lane >> 4) * 4 + rr;
                float v = acc[m][rr] + bv;
                if (EPI == 1) outB[(size_t)row * Nout + col] = f2bf(lrelu(v));
                else          outF[(size_t)row * Nout + col] = v;
            }
    }
}

// ---------------------------------------------------------------------------
// gemmBN: 256 thr = 4 waves stacked in M (32 rows each), 16 cols, full-K B
// preload, fused BatchNorm (bias cancels) + lrelu -> bf16. grid (Nout/16).
// ZIN: A built on the fly as z = mu + eps*exp(0.5*lv) (fp32 inputs).
// ---------------------------------------------------------------------------
template<int K32, bool ZIN>
__global__ __launch_bounds__(256) void gemmBN(
    const short* __restrict__ A, const float* __restrict__ muv,
    const float* __restrict__ lvv, const float* __restrict__ eps,
    const short* __restrict__ Wfrag,
    const float* __restrict__ g, const float* __restrict__ be,
    short* __restrict__ outB, int Nout)
{
    __shared__ float bns[4][16];
    __shared__ float bnq[4][16];

    const int tid = threadIdx.x, lane = tid & 63, w = tid >> 6;
    const int cbb = blockIdx.x;
    const int K = K32 * 32;
    const int t = cbb >> 2, n = cbb & 3;

    short8 bf[K32];
#pragma unroll
    for (int ks = 0; ks < K32; ++ks)
        bf[ks] = *(const short8*)&Wfrag[(size_t)((t * K32 + ks) * 4 + n) * 512 + lane * 8];

    const int arow0 = w * 32 + (lane & 15);
    const int koff  = (lane >> 4) * 8;
    f32x4 acc[2];
    acc[0] = 0; acc[1] = 0;
#pragma unroll
    for (int ks = 0; ks < K32; ++ks) {
        short8 a0, a1;
        if (ZIN) {
#pragma unroll
            for (int e = 0; e < 8; ++e) {
                int k = ks * 32 + koff + e;
                size_t i0 = (size_t)arow0 * 256 + k;
                size_t i1 = (size_t)(arow0 + 16) * 256 + k;
                a0[e] = f2bf(fmaf(eps[i0], expf(0.5f * lvv[i0]), muv[i0]));
                a1[e] = f2bf(fmaf(eps[i1], expf(0.5f * lvv[i1]), muv[i1]));
            }
        } else {
            a0 = *(const short8*)&A[(size_t)arow0 * K + ks * 32 + koff];
            a1 = *(const short8*)&A[(size_t)(arow0 + 16) * K + ks * 32 + koff];
        }
        acc[0] = __builtin_amdgcn_mfma_f32_16x16x32_bf16(a0, bf[ks], acc[0], 0, 0, 0);
        acc[1] = __builtin_amdgcn_mfma_f32_16x16x32_bf16(a1, bf[ks], acc[1], 0, 0, 0);
    }

    // BN stats over the block's 128 rows
    float s = 0.f, q = 0.f;
#pragma unroll
    for (int m = 0; m < 2; ++m)
#pragma unroll
        for (int rr = 0; rr < 4; ++rr) {
            float v = acc[m][rr];
            s += v; q = fmaf(v, v, q);
        }
    s += __shfl_xor(s, 16); s += __shfl_xor(s, 32);
    q += __shfl_xor(q, 16); q += __shfl_xor(q, 32);
    if (lane < 16) { bns[w][lane] = s; bnq[w][lane] = q; }
    __syncthreads();

    const int cl = lane & 15;
    float st = bns[0][cl] + bns[1][cl] + bns[2][cl] + bns[3][cl];
    float qt = bnq[0][cl] + bnq[1][cl] + bnq[2][cl] + bnq[3][cl];
    float mean = st * (1.0f / 128.0f);
    float var  = qt * (1.0f / 128.0f) - mean * mean;
    float rs   = 1.0f / sqrtf(var + 1e-5f);
    const int col = cbb * 16 + cl;
    float gg = g[col] * rs;
    float bb = be[col] - mean * gg;

#pragma unroll
    for (int m = 0; m < 2; ++m)
#pragma unroll
        for (int rr = 0; rr < 4; ++rr) {
            int row = w * 32 + m * 16 + (lane >> 4) * 4 + rr;
            outB[(size_t)row * Nout + col] = f2bf(lrelu(fmaf(acc[m][rr], gg, bb)));
        }
}

// ---------------------------------------------------------------------------
extern "C" void kernel_launch(void* const* d_in, const int* in_sizes, int n_in,
                              void* d_out, int out_size, void* d_ws, size_t ws_size,
                              hipStream_t stream)
{
    const float* x       = (const float*)d_in[0];
    const int*   lengths = (const int*)  d_in[1];
    const float* eps     = (const float*)d_in[2];
    const float* W1  = (const float*)d_in[3];  const float* b1  = (const float*)d_in[4];
    const float* W2  = (const float*)d_in[5];  const float* b2  = (const float*)d_in[6];
    const float* W3  = (const float*)d_in[7];  const float* b3  = (const float*)d_in[8];
    const float* W4  = (const float*)d_in[9];  const float* b4  = (const float*)d_in[10];
    const float* Wf  = (const float*)d_in[11]; const float* bf  = (const float*)d_in[12];
    const float* Wmu = (const float*)d_in[13]; const float* bmu = (const float*)d_in[14];
    const float* Wlv = (const float*)d_in[15]; const float* blv = (const float*)d_in[16];
    const float* Wd1 = (const float*)d_in[17];
    const float* g1  = (const float*)d_in[19]; const float* be1 = (const float*)d_in[20];
    const float* Wd2 = (const float*)d_in[21];
    const float* g2  = (const float*)d_in[23]; const float* be2 = (const float*)d_in[24];
    const float* Wd3 = (const float*)d_in[25]; const float* bd3 = (const float*)d_in[26];
    // bd1, bd2 provably cancel inside BatchNorm

    float* out = (float*)d_out;
    float* y_out  = out;               // [128,384]
    float* mu_out = out + 49152;       // [128,256]
    float* lv_out = out + 81920;       // [128,256]

    // ---- workspace layout (bytes) ----
    char* ws = (char*)d_ws;
    short* F4    = (short*)(ws + 0);
    short* Ff    = (short*)(ws + 262144);
    short* Fmuvl = (short*)(ws + 2359296);
    short* Fd1   = (short*)(ws + 3407872);
    short* Fd2   = (short*)(ws + 3932160);
    short* Fd3   = (short*)(ws + 6029312);
    short* F2    = (short*)(ws + 6815744);
    short* F3    = (short*)(ws + 6823936);
    short* h3p   = (short*)(ws + 6840320);     // 64MB (dead after l4_pool)
    float* part  = (float*)(ws + 73949184);    // 128*8*1024 f32 = 4MB
    // post-l4 buffers overlay the (dead) h3p region:
    short* pooled = (short*)(ws + 6840320 + 0);
    short* ebuf   = (short*)(ws + 6840320 + 262144);
    short* d1v    = (short*)(ws + 6840320 + 524288);
    short* d2v    = (short*)(ws + 6840320 + 786432);

    // 0) pack all MFMA weights
    pack_all<<<1670, 256, 0, stream>>>(W4, Wf, Wmu, Wlv, Wd1, Wd2, Wd3, W2, W3,
                                       F4, Ff, Fmuvl, Fd1, Fd2, Fd3, F2, F3);
    // 1) per-point MLP -> packed h3 fragments
    h3_kernel<<<2048, 128, 0, stream>>>(x, lengths, W1, b1, b2, b3, F2, F3, h3p);
    // 2) L4 + masked max-pool (v6 schedule, occupancy hint 4: cap 128 > 84)
    l4_pool_kernel<<<dim3(128, 4, 8), 256, 0, stream>>>(h3p, lengths, F4, part);
    // 3) finish pool (+b4, lrelu) -> pooled bf16
    reduce_pool_kernel<<<128, 256, 0, stream>>>(part, lengths, b4, pooled);
    // 4) e = lrelu(pooled @ Wf + bf) -> bf16
    gemm16<32, 1><<<dim3(64, 4), 64, 0, stream>>>(pooled, Ff, bf, nullptr,
                                                  nullptr, nullptr, ebuf, 1024);
    // 5) mu | logvar (fp32 straight to d_out)
    gemm16<32, 2><<<dim3(32, 4), 64, 0, stream>>>(ebuf, Fmuvl, bmu, blv,
                                                  mu_out, lv_out, nullptr, 256);
    // 6) decoder 1: z built on the fly (mu,lv,eps), Linear+BN+lrelu -> bf16
    gemmBN<8, true><<<64, 256, 0, stream>>>(nullptr, mu_out, lv_out, eps,
                                            Fd1, g1, be1, d1v, 1024);
    // 7) decoder 2: Linear+BN+lrelu -> bf16
    gemmBN<32, false><<<64, 256, 0, stream>>>(d1v, nullptr, nullptr, nullptr,
                                              Fd2, g2, be2, d2v, 1024);
    // 8) final linear -> y (fp32)
    gemm16<32, 0><<<dim3(24, 4), 64, 0, stream>>>(d2v, Fd3, bd3, nullptr,
                                                  y_out, nullptr, nullptr, 384);
}

// Round 19
// 119.891 us; speedup vs baseline: 2.5509x; 1.7191x over previous
//
#include <hip/hip_runtime.h>
#include <hip/hip_bf16.h>
#include <math.h>

#define NEG_SLOPE 0.01f

typedef short short8 __attribute__((ext_vector_type(8)));
typedef float f32x4 __attribute__((ext_vector_type(4)));

__device__ __forceinline__ float lrelu(float v) { return v > 0.0f ? v : NEG_SLOPE * v; }

__device__ __forceinline__ short f2bf(float f) {
    __hip_bfloat16 h = __float2bfloat16(f);
    return __builtin_bit_cast(short, h);
}

// ---------------------------------------------------------------------------
// pack_all: fp32 [K][N] -> bf16 fragment-native layout.
// frag f = ((t*K32 + ks)*4 + n); lane l, elem e:
//   col = t*64 + n*16 + (l&15), k = ks*32 + (l>>4)*8 + e
// ---------------------------------------------------------------------------
__global__ __launch_bounds__(256) void pack_all(
    const float* __restrict__ W4, const float* __restrict__ Wf,
    const float* __restrict__ Wmu, const float* __restrict__ Wlv,
    const float* __restrict__ Wd1, const float* __restrict__ Wd2,
    const float* __restrict__ Wd3, const float* __restrict__ W2,
    const float* __restrict__ W3,
    short* __restrict__ F4, short* __restrict__ Ff, short* __restrict__ Fmuvl,
    short* __restrict__ Fd1, short* __restrict__ Fd2, short* __restrict__ Fd3,
    short* __restrict__ F2, short* __restrict__ F3)
{
    int bid = blockIdx.x;
    const float* src = nullptr; short* dst = nullptr; int K = 0, N = 0; int muvl = 0;
    if      (bid < 64)   { src = W4;  dst = F4;    K = 128;  N = 1024; }
    else if (bid < 576)  { src = Wf;  dst = Ff;    K = 1024; N = 1024; bid -= 64; }
    else if (bid < 832)  { src = nullptr; dst = Fmuvl; K = 1024; N = 512; muvl = 1; bid -= 576; }
    else if (bid < 960)  { src = Wd1; dst = Fd1;   K = 256;  N = 1024; bid -= 832; }
    else if (bid < 1472) { src = Wd2; dst = Fd2;   K = 1024; N = 1024; bid -= 960; }
    else if (bid < 1664) { src = Wd3; dst = Fd3;   K = 1024; N = 384;  bid -= 1472; }
    else if (bid < 1666) { src = W2;  dst = F2;    K = 64;   N = 64;   bid -= 1664; }
    else                 { src = W3;  dst = F3;    K = 64;   N = 128;  bid -= 1666; }

    const int fragid = bid * 4 + (threadIdx.x >> 6);
    const int lane   = threadIdx.x & 63;
    const int K32    = K >> 5;
    const int t   = fragid / (K32 * 4);
    const int rem = fragid - t * K32 * 4;
    const int ks  = rem >> 2;
    const int n   = rem & 3;
    const int col   = t * 64 + n * 16 + (lane & 15);
    const int kbase = ks * 32 + (lane >> 4) * 8;

    short8 v;
#pragma unroll
    for (int e = 0; e < 8; ++e) {
        float f;
        if (muvl) f = (col < 256) ? Wmu[(size_t)(kbase + e) * 256 + col]
                                  : Wlv[(size_t)(kbase + e) * 256 + col - 256];
        else      f = src[(size_t)(kbase + e) * N + col];
        v[e] = f2bf(f);
    }
    *(short8*)&dst[(size_t)fragid * 512 + lane * 8] = v;
}

// ---------------------------------------------------------------------------
// h3_kernel: per-point MLP 3->64->64->128, barrier-free, wave-private LDS.
// Output: A-fragments packed to global:
//   h3p[((b*32+g)*16 + ks*4+m)*512 + lane*8]
// ---------------------------------------------------------------------------
__global__ __launch_bounds__(128, 2) void h3_kernel(
    const float* __restrict__ x, const int* __restrict__ lengths,
    const float* __restrict__ W1, const float* __restrict__ b1,
    const float* __restrict__ b2, const float* __restrict__ b3,
    const short* __restrict__ F2, const short* __restrict__ F3,
    short* __restrict__ h3p)
{
    const int tid  = threadIdx.x;
    const int b    = blockIdx.x & 127;
    const int c2   = blockIdx.x >> 7;
    const int lane = tid & 63;
    const int w    = tid >> 6;
    const int g    = c2 * 2 + w;
    const int len  = lengths[b];
    if (g * 64 >= len) return;

    __shared__ short S[16384];
    short* Aw = S + w * 8192;
    const int gid = b * 2048 + g * 64 + lane;

    {   // P0: h1
        const float x0 = x[gid * 3 + 0];
        const float x1 = x[gid * 3 + 1];
        const float x2 = x[gid * 3 + 2];
#pragma unroll
        for (int q = 0; q < 8; ++q) {
            short8 pv;
#pragma unroll
            for (int e = 0; e < 8; ++e) {
                int c = q * 8 + e;
                float v = b1[c];
                v = fmaf(x0, W1[c], v);
                v = fmaf(x1, W1[64 + c], v);
                v = fmaf(x2, W1[128 + c], v);
                pv[e] = f2bf(lrelu(v));
            }
            *(short8*)&Aw[lane * 64 + ((q ^ (lane & 7)) * 8)] = pv;
        }
    }

    {   // L2
        short8 a2[4][2];
#pragma unroll
        for (int m = 0; m < 4; ++m)
#pragma unroll
            for (int ks = 0; ks < 2; ++ks) {
                int rl = m * 16 + (lane & 15);
                int kch = ks * 4 + (lane >> 4);
                a2[m][ks] = *(const short8*)&Aw[rl * 64 + ((kch ^ (rl & 7)) * 8)];
            }
        short8 b2f[2][4];
#pragma unroll
        for (int ks = 0; ks < 2; ++ks)
#pragma unroll
            for (int n = 0; n < 4; ++n)
                b2f[ks][n] = *(const short8*)&F2[(size_t)(ks * 4 + n) * 512 + lane * 8];

        f32x4 acc2[4][4];
#pragma unroll
        for (int m = 0; m < 4; ++m)
#pragma unroll
            for (int n = 0; n < 4; ++n) acc2[m][n] = 0;
#pragma unroll
        for (int ks = 0; ks < 2; ++ks)
#pragma unroll
            for (int n = 0; n < 4; ++n)
#pragma unroll
                for (int m = 0; m < 4; ++m)
                    acc2[m][n] = __builtin_amdgcn_mfma_f32_16x16x32_bf16(
                        a2[m][ks], b2f[ks][n], acc2[m][n], 0, 0, 0);

#pragma unroll
        for (int n = 0; n < 4; ++n) {
            int col = n * 16 + (lane & 15);
            float bv = b2[col];
            int colch = col >> 3;
#pragma unroll
            for (int m = 0; m < 4; ++m)
#pragma unroll
                for (int r = 0; r < 4; ++r) {
                    int rl = m * 16 + (lane >> 4) * 4 + r;
                    Aw[4096 + rl * 64 + ((colch ^ (rl & 7)) * 8) + (col & 7)] =
                        f2bf(lrelu(acc2[m][n][r] + bv));
                }
        }
    }

    {   // L3
        short8 a3[4][2];
#pragma unroll
        for (int m = 0; m < 4; ++m)
#pragma unroll
            for (int ks = 0; ks < 2; ++ks) {
                int rl = m * 16 + (lane & 15);
                int kch = ks * 4 + (lane >> 4);
                a3[m][ks] = *(const short8*)&Aw[4096 + rl * 64 + ((kch ^ (rl & 7)) * 8)];
            }
#pragma unroll
        for (int half = 0; half < 2; ++half) {
            short8 b3f[2][4];
#pragma unroll
            for (int ks = 0; ks < 2; ++ks)
#pragma unroll
                for (int n = 0; n < 4; ++n)
                    b3f[ks][n] = *(const short8*)&F3[(size_t)(half * 8 + ks * 4 + n) * 512 + lane * 8];

            f32x4 acc3[4][4];
#pragma unroll
            for (int m = 0; m < 4; ++m)
#pragma unroll
                for (int n = 0; n < 4; ++n) acc3[m][n] = 0;
#pragma unroll
            for (int ks = 0; ks < 2; ++ks)
#pragma unroll
                for (int n = 0; n < 4; ++n)
#pragma unroll
                    for (int m = 0; m < 4; ++m)
                        acc3[m][n] = __builtin_amdgcn_mfma_f32_16x16x32_bf16(
                            a3[m][ks], b3f[ks][n], acc3[m][n], 0, 0, 0);

#pragma unroll
            for (int n = 0; n < 4; ++n) {
                int col = half * 64 + n * 16 + (lane & 15);
                float bv = b3[col];
                int colch = col >> 3;
#pragma unroll
                for (int m = 0; m < 4; ++m)
#pragma unroll
                    for (int r = 0; r < 4; ++r) {
                        int rl = m * 16 + (lane >> 4) * 4 + r;
                        Aw[rl * 128 + ((colch ^ (rl & 7)) * 8) + (col & 7)] =
                            f2bf(lrelu(acc3[m][n][r] + bv));
                    }
            }
        }
    }

    const size_t obase = ((size_t)(b * 32 + g) * 16) * 512 + lane * 8;
#pragma unroll
    for (int ks = 0; ks < 4; ++ks)
#pragma unroll
        for (int m = 0; m < 4; ++m) {
            int rl = m * 16 + (lane & 15);
            int ch = (ks * 4 + (lane >> 4)) ^ (rl & 7);
            short8 af = *(const short8*)&Aw[rl * 128 + ch * 8];
            *(short8*)&h3p[obase + (size_t)(ks * 4 + m) * 512] = af;
        }
}

// ---------------------------------------------------------------------------
// l4_pool v6 (round-11 best, hint 3): 64-row chunks, 2x16KB LDS double
// buffer, ONE barrier per chunk. grid (128 b, 4 ch, 8 rs).
// ---------------------------------------------------------------------------
__global__ __launch_bounds__(256, 3) void l4_pool_kernel(
    const short* __restrict__ h3p, const int* __restrict__ lengths,
    const short* __restrict__ F4, float* __restrict__ part)
{
    const int tid = threadIdx.x, lane = tid & 63, w = tid >> 6;
    const int b = blockIdx.x, ch = blockIdx.y, rs = blockIdx.z;
    const int len = lengths[b];
    const int live64 = (len + 63) >> 6;
    const int cbeg = rs * 4;
    int cend = cbeg + 4; if (cend > live64) cend = live64;
    if (cbeg >= cend) return;

    __shared__ short L[16384];                   // 2 x 8192-short (16KB) buffers

    const int t = ch * 4 + w;
    short8 bfr[4][4];
#pragma unroll
    for (int ks = 0; ks < 4; ++ks)
#pragma unroll
        for (int n = 0; n < 4; ++n)
            bfr[ks][n] = *(const short8*)&F4[(size_t)((t * 4 + ks) * 4 + n) * 512 + lane * 8];

    const int partial = (len & 63) ? (live64 - 1) : -1;
    const int rem = len & 63;

    f32x4 rmax[4];
#pragma unroll
    for (int n = 0; n < 4; ++n)
#pragma unroll
        for (int rr = 0; rr < 4; ++rr) rmax[n][rr] = -INFINITY;

    const size_t bb = (size_t)b * 32;
    short8 stg[4];
    {   // prolog: stage chunk cbeg into buf0
        const size_t fb = (bb + cbeg) * 16 * 512;
#pragma unroll
        for (int pass = 0; pass < 4; ++pass)
            stg[pass] = *(const short8*)&h3p[fb + (size_t)(pass * 256 + tid) * 8];
#pragma unroll
        for (int pass = 0; pass < 4; ++pass)
            *(short8*)&L[(pass * 256 + tid) * 8] = stg[pass];
    }
    __syncthreads();

    for (int c = cbeg; c < cend; ++c) {
        const int p2 = (c - cbeg) & 1;
        if (c + 1 < cend) {
            const size_t fb = (bb + c + 1) * 16 * 512;
#pragma unroll
            for (int pass = 0; pass < 4; ++pass)
                stg[pass] = *(const short8*)&h3p[fb + (size_t)(pass * 256 + tid) * 8];
        }

        const short* Lb = L + p2 * 8192;
#pragma unroll
        for (int mh = 0; mh < 2; ++mh) {
            f32x4 acc[2][4];
#pragma unroll
            for (int j = 0; j < 2; ++j)
#pragma unroll
                for (int n = 0; n < 4; ++n) acc[j][n] = 0;
#pragma unroll
            for (int ks = 0; ks < 4; ++ks) {
                short8 a0 = *(const short8*)&Lb[(ks * 4 + mh * 2 + 0) * 512 + lane * 8];
                short8 a1 = *(const short8*)&Lb[(ks * 4 + mh * 2 + 1) * 512 + lane * 8];
#pragma unroll
                for (int n = 0; n < 4; ++n) {
                    acc[0][n] = __builtin_amdgcn_mfma_f32_16x16x32_bf16(a0, bfr[ks][n], acc[0][n], 0, 0, 0);
                    acc[1][n] = __builtin_amdgcn_mfma_f32_16x16x32_bf16(a1, bfr[ks][n], acc[1][n], 0, 0, 0);
                }
            }
            if (c == partial) {
#pragma unroll
                for (int j = 0; j < 2; ++j)
#pragma unroll
                    for (int n = 0; n < 4; ++n)
#pragma unroll
                        for (int rr = 0; rr < 4; ++rr) {
                            int row = mh * 32 + j * 16 + (lane >> 4) * 4 + rr;
                            rmax[n][rr] = fmaxf(rmax[n][rr],
                                (row < rem) ? acc[j][n][rr] : -INFINITY);
                        }
            } else {
#pragma unroll
                for (int j = 0; j < 2; ++j)
#pragma unroll
                    for (int n = 0; n < 4; ++n)
#pragma unroll
                        for (int rr = 0; rr < 4; ++rr)
                            rmax[n][rr] = fmaxf(rmax[n][rr], acc[j][n][rr]);
            }
        }

        if (c + 1 < cend) {
            short* Ln = L + (p2 ^ 1) * 8192;
#pragma unroll
            for (int pass = 0; pass < 4; ++pass)
                *(short8*)&Ln[(pass * 256 + tid) * 8] = stg[pass];
        }
        __syncthreads();
    }

#pragma unroll
    for (int n = 0; n < 4; ++n) {
        float v = fmaxf(fmaxf(rmax[n][0], rmax[n][1]), fmaxf(rmax[n][2], rmax[n][3]));
        v = fmaxf(v, __shfl_xor(v, 16));
        v = fmaxf(v, __shfl_xor(v, 32));
        if (lane < 16)
            part[((size_t)b * 8 + rs) * 1024 + ch * 256 + w * 64 + n * 16 + lane] = v;
    }
}

// ---------------------------------------------------------------------------
// reduce: fold live row-slice partials, + b4, lrelu -> pooled bf16.
// ---------------------------------------------------------------------------
__global__ __launch_bounds__(256) void reduce_pool_kernel(
    const float* __restrict__ part, const int* __restrict__ lengths,
    const float* __restrict__ b4, short* __restrict__ pooled)
{
    const int b = blockIdx.x;
    const int nlive = (lengths[b] + 255) >> 8;   // 1..8
    for (int i = threadIdx.x; i < 1024; i += 256) {
        float m = part[((size_t)b * 8 + 0) * 1024 + i];
        for (int j = 1; j < nlive; ++j)
            m = fmaxf(m, part[((size_t)b * 8 + j) * 1024 + i]);
        pooled[(size_t)b * 1024 + i] = f2bf(lrelu(m + b4[i]));
    }
}

// ---------------------------------------------------------------------------
// gemm16: 1-wave blocks, 16 cols x 32 rows per wave, FULL-K B preload.
// grid (Nout/16, 4 rowhalves). EPI: 0 = bias->fp32, 1 = bias+lrelu->bf16,
// 2 = mu|lv split (c0<256 -> bias/outF, else bias2/outF2, fp32).
// ---------------------------------------------------------------------------
template<int K32, int EPI>
__global__ __launch_bounds__(64) void gemm16(
    const short* __restrict__ A, const short* __restrict__ Wfrag,
    const float* __restrict__ bias, const float* __restrict__ bias2,
    float* __restrict__ outF, float* __restrict__ outF2,
    short* __restrict__ outB, int Nout)
{
    const int lane = threadIdx.x;
    const int cbb = blockIdx.x, rh = blockIdx.y;
    const int K = K32 * 32;
    const int t = cbb >> 2, n = cbb & 3;

    short8 bf[K32];
#pragma unroll
    for (int ks = 0; ks < K32; ++ks)
        bf[ks] = *(const short8*)&Wfrag[(size_t)((t * K32 + ks) * 4 + n) * 512 + lane * 8];

    const int arow0 = rh * 32 + (lane & 15);
    const int koff  = (lane >> 4) * 8;
    f32x4 acc[2];
    acc[0] = 0; acc[1] = 0;
#pragma unroll
    for (int ks = 0; ks < K32; ++ks) {
        short8 a0 = *(const short8*)&A[(size_t)arow0 * K + ks * 32 + koff];
        short8 a1 = *(const short8*)&A[(size_t)(arow0 + 16) * K + ks * 32 + koff];
        acc[0] = __builtin_amdgcn_mfma_f32_16x16x32_bf16(a0, bf[ks], acc[0], 0, 0, 0);
        acc[1] = __builtin_amdgcn_mfma_f32_16x16x32_bf16(a1, bf[ks], acc[1], 0, 0, 0);
    }

    const int c0 = cbb * 16;
    const int cl = lane & 15;
    if (EPI == 2) {
        const float* bs = (c0 < 256) ? bias : bias2;
        float* of = (c0 < 256) ? outF : outF2;
        int col = (c0 & 255) + cl;
        float bv = bs[col];
#pragma unroll
        for (int m = 0; m < 2; ++m)
#pragma unroll
            for (int rr = 0; rr < 4; ++rr) {
                int row = rh * 32 + m * 16 + (lane >> 4) * 4 + rr;
                of[(size_t)row * 256 + col] = acc[m][rr] + bv;
            }
    } else {
        int col = c0 + cl;
        float bv = bias[col];
#pragma unroll
        for (int m = 0; m < 2; ++m)
#pragma unroll
            for (int rr = 0; rr < 4; ++rr) {
                int row = rh * 32 + m * 16 + (lane >> 4) * 4 + rr;
                float v = acc[m][rr] + bv;
                if (EPI == 1) outB[(size_t)row * Nout + col] = f2bf(lrelu(v));
                else          outF[(size_t)row * Nout + col] = v;
            }
    }
}

// ---------------------------------------------------------------------------
// gemmBN: 256 thr = 4 waves stacked in M (32 rows each), 16 cols, full-K B
// preload, fused BatchNorm (bias cancels) + lrelu -> bf16. grid (Nout/16).
// ZIN: A built on the fly as z = mu + eps*exp(0.5*lv) (fp32 inputs).
// ---------------------------------------------------------------------------
template<int K32, bool ZIN>
__global__ __launch_bounds__(256) void gemmBN(
    const short* __restrict__ A, const float* __restrict__ muv,
    const float* __restrict__ lvv, const float* __restrict__ eps,
    const short* __restrict__ Wfrag,
    const float* __restrict__ g, const float* __restrict__ be,
    short* __restrict__ outB, int Nout)
{
    __shared__ float bns[4][16];
    __shared__ float bnq[4][16];

    const int tid = threadIdx.x, lane = tid & 63, w = tid >> 6;
    const int cbb = blockIdx.x;
    const int K = K32 * 32;
    const int t = cbb >> 2, n = cbb & 3;

    short8 bf[K32];
#pragma unroll
    for (int ks = 0; ks < K32; ++ks)
        bf[ks] = *(const short8*)&Wfrag[(size_t)((t * K32 + ks) * 4 + n) * 512 + lane * 8];

    const int arow0 = w * 32 + (lane & 15);
    const int koff  = (lane >> 4) * 8;
    f32x4 acc[2];
    acc[0] = 0; acc[1] = 0;
#pragma unroll
    for (int ks = 0; ks < K32; ++ks) {
        short8 a0, a1;
        if (ZIN) {
#pragma unroll
            for (int e = 0; e < 8; ++e) {
                int k = ks * 32 + koff + e;
                size_t i0 = (size_t)arow0 * 256 + k;
                size_t i1 = (size_t)(arow0 + 16) * 256 + k;
                a0[e] = f2bf(fmaf(eps[i0], expf(0.5f * lvv[i0]), muv[i0]));
                a1[e] = f2bf(fmaf(eps[i1], expf(0.5f * lvv[i1]), muv[i1]));
            }
        } else {
            a0 = *(const short8*)&A[(size_t)arow0 * K + ks * 32 + koff];
            a1 = *(const short8*)&A[(size_t)(arow0 + 16) * K + ks * 32 + koff];
        }
        acc[0] = __builtin_amdgcn_mfma_f32_16x16x32_bf16(a0, bf[ks], acc[0], 0, 0, 0);
        acc[1] = __builtin_amdgcn_mfma_f32_16x16x32_bf16(a1, bf[ks], acc[1], 0, 0, 0);
    }

    // BN stats over the block's 128 rows
    float s = 0.f, q = 0.f;
#pragma unroll
    for (int m = 0; m < 2; ++m)
#pragma unroll
        for (int rr = 0; rr < 4; ++rr) {
            float v = acc[m][rr];
            s += v; q = fmaf(v, v, q);
        }
    s += __shfl_xor(s, 16); s += __shfl_xor(s, 32);
    q += __shfl_xor(q, 16); q += __shfl_xor(q, 32);
    if (lane < 16) { bns[w][lane] = s; bnq[w][lane] = q; }
    __syncthreads();

    const int cl = lane & 15;
    float st = bns[0][cl] + bns[1][cl] + bns[2][cl] + bns[3][cl];
    float qt = bnq[0][cl] + bnq[1][cl] + bnq[2][cl] + bnq[3][cl];
    float mean = st * (1.0f / 128.0f);
    float var  = qt * (1.0f / 128.0f) - mean * mean;
    float rs   = 1.0f / sqrtf(var + 1e-5f);
    const int col = cbb * 16 + cl;
    float gg = g[col] * rs;
    float bb = be[col] - mean * gg;

#pragma unroll
    for (int m = 0; m < 2; ++m)
#pragma unroll
        for (int rr = 0; rr < 4; ++rr) {
            int row = w * 32 + m * 16 + (lane >> 4) * 4 + rr;
            outB[(size_t)row * Nout + col] = f2bf(lrelu(fmaf(acc[m][rr], gg, bb)));
        }
}

// ---------------------------------------------------------------------------
extern "C" void kernel_launch(void* const* d_in, const int* in_sizes, int n_in,
                              void* d_out, int out_size, void* d_ws, size_t ws_size,
                              hipStream_t stream)
{
    const float* x       = (const float*)d_in[0];
    const int*   lengths = (const int*)  d_in[1];
    const float* eps     = (const float*)d_in[2];
    const float* W1  = (const float*)d_in[3];  const float* b1  = (const float*)d_in[4];
    const float* W2  = (const float*)d_in[5];  const float* b2  = (const float*)d_in[6];
    const float* W3  = (const float*)d_in[7];  const float* b3  = (const float*)d_in[8];
    const float* W4  = (const float*)d_in[9];  const float* b4  = (const float*)d_in[10];
    const float* Wf  = (const float*)d_in[11]; const float* bf  = (const float*)d_in[12];
    const float* Wmu = (const float*)d_in[13]; const float* bmu = (const float*)d_in[14];
    const float* Wlv = (const float*)d_in[15]; const float* blv = (const float*)d_in[16];
    const float* Wd1 = (const float*)d_in[17];
    const float* g1  = (const float*)d_in[19]; const float* be1 = (const float*)d_in[20];
    const float* Wd2 = (const float*)d_in[21];
    const float* g2  = (const float*)d_in[23]; const float* be2 = (const float*)d_in[24];
    const float* Wd3 = (const float*)d_in[25]; const float* bd3 = (const float*)d_in[26];
    // bd1, bd2 provably cancel inside BatchNorm

    float* out = (float*)d_out;
    float* y_out  = out;               // [128,384]
    float* mu_out = out + 49152;       // [128,256]
    float* lv_out = out + 81920;       // [128,256]

    // ---- workspace layout (bytes) ----
    char* ws = (char*)d_ws;
    short* F4    = (short*)(ws + 0);
    short* Ff    = (short*)(ws + 262144);
    short* Fmuvl = (short*)(ws + 2359296);
    short* Fd1   = (short*)(ws + 3407872);
    short* Fd2   = (short*)(ws + 3932160);
    short* Fd3   = (short*)(ws + 6029312);
    short* F2    = (short*)(ws + 6815744);
    short* F3    = (short*)(ws + 6823936);
    short* h3p   = (short*)(ws + 6840320);     // 64MB (dead after l4_pool)
    float* part  = (float*)(ws + 73949184);    // 128*8*1024 f32 = 4MB
    // post-l4 buffers overlay the (dead) h3p region:
    short* pooled = (short*)(ws + 6840320 + 0);
    short* ebuf   = (short*)(ws + 6840320 + 262144);
    short* d1v    = (short*)(ws + 6840320 + 524288);
    short* d2v    = (short*)(ws + 6840320 + 786432);

    // 0) pack all MFMA weights
    pack_all<<<1670, 256, 0, stream>>>(W4, Wf, Wmu, Wlv, Wd1, Wd2, Wd3, W2, W3,
                                       F4, Ff, Fmuvl, Fd1, Fd2, Fd3, F2, F3);
    // 1) per-point MLP -> packed h3 fragments
    h3_kernel<<<2048, 128, 0, stream>>>(x, lengths, W1, b1, b2, b3, F2, F3, h3p);
    // 2) L4 + masked max-pool (v6 schedule, hint 3 -- measured best)
    l4_pool_kernel<<<dim3(128, 4, 8), 256, 0, stream>>>(h3p, lengths, F4, part);
    // 3) finish pool (+b4, lrelu) -> pooled bf16
    reduce_pool_kernel<<<128, 256, 0, stream>>>(part, lengths, b4, pooled);
    // 4) e = lrelu(pooled @ Wf + bf) -> bf16
    gemm16<32, 1><<<dim3(64, 4), 64, 0, stream>>>(pooled, Ff, bf, nullptr,
                                                  nullptr, nullptr, ebuf, 1024);
    // 5) mu | logvar (fp32 straight to d_out)
    gemm16<32, 2><<<dim3(32, 4), 64, 0, stream>>>(ebuf, Fmuvl, bmu, blv,
                                                  mu_out, lv_out, nullptr, 256);
    // 6) decoder 1: z built on the fly (mu,lv,eps), Linear+BN+lrelu -> bf16
    gemmBN<8, true><<<64, 256, 0, stream>>>(nullptr, mu_out, lv_out, eps,
                                            Fd1, g1, be1, d1v, 1024);
    // 7) decoder 2: Linear+BN+lrelu -> bf16
    gemmBN<32, false><<<64, 256, 0, stream>>>(d1v, nullptr, nullptr, nullptr,
                                              Fd2, g2, be2, d2v, 1024);
    // 8) final linear -> y (fp32)
    gemm16<32, 0><<<dim3(24, 4), 64, 0, stream>>>(d2v, Fd3, bd3, nullptr,
                                                  y_out, nullptr, nullptr, 384);
}